// Round 1
// baseline (469.727 us; speedup 1.0000x reference)
//
#include <hip/hip_runtime.h>
#include <hip/hip_bf16.h>

#define DIM   1024
#define HEADS 16
#define HD    64
#define BB    2
#define LL    2048
#define MTOT  (BB*LL)   // 4096
#define EPSV  1.1920928955078125e-07f

typedef __attribute__((ext_vector_type(8))) short bf16x8;
typedef __attribute__((ext_vector_type(4))) float f32x4;
typedef unsigned short ushort_t;

__device__ __forceinline__ float bf2f(ushort_t u) {
    unsigned int x = ((unsigned int)u) << 16;
    return __builtin_bit_cast(float, x);
}
__device__ __forceinline__ ushort_t f2bf(float f) {
    unsigned int x = __builtin_bit_cast(unsigned int, f);
    unsigned int r = (x + 0x7FFFu + ((x >> 16) & 1u)) >> 16;
    return (ushort_t)r;
}

// ---------------- fp32 -> bf16 convert (vectorized) ----------------
__global__ __launch_bounds__(256) void f32_to_bf16_k(const float* __restrict__ in,
                                                     ushort_t* __restrict__ out, int n) {
    int i = (blockIdx.x * 256 + threadIdx.x) * 4;
    if (i < n) {
        float4 v = *(const float4*)(in + i);
        ushort4 o;
        o.x = f2bf(v.x); o.y = f2bf(v.y); o.z = f2bf(v.z); o.w = f2bf(v.w);
        *(ushort4*)(out + i) = o;
    }
}

// ---------------- GEMM: C[M][N] = A[M][K] * Bt[N][K]^T + bias ----------------
// 128x128 tile, 4 waves (2x2), each wave 64x64 via 4x4 MFMA 16x16x32 tiles.
template <int OUT_BF16>
__global__ __launch_bounds__(256) void gemm_bt(const ushort_t* __restrict__ A,
                                               const ushort_t* __restrict__ Bt,
                                               const float* __restrict__ bias,
                                               void* __restrict__ Cout,
                                               int M, int N, int K) {
    __shared__ __attribute__((aligned(16))) ushort_t Asm[128 * 32];
    __shared__ __attribute__((aligned(16))) ushort_t Bsm[128 * 32];
    int tid = threadIdx.x;
    int lane = tid & 63, wid = tid >> 6;
    int wm = wid >> 1, wn = wid & 1;
    int r = lane & 15, g = lane >> 4;
    int m0 = blockIdx.y * 128, n0 = blockIdx.x * 128;

    f32x4 acc[4][4] = {};

    int niter = K >> 5;
    for (int kk = 0; kk < niter; ++kk) {
        int k0 = kk << 5;
        __syncthreads();  // protect LDS against previous iteration's readers
#pragma unroll
        for (int p = 0; p < 2; ++p) {
            int off = (p * 256 + tid) * 8;          // bf16 element offset in tile
            int row = off >> 5, col = off & 31;
            int ldsoff = (p * 256 + wid * 64) * 8;  // wave-uniform LDS base (elements)
            __builtin_amdgcn_global_load_lds(
                (const __attribute__((address_space(1))) void*)(A + (size_t)(m0 + row) * K + k0 + col),
                (__attribute__((address_space(3))) void*)(Asm + ldsoff), 16, 0, 0);
            __builtin_amdgcn_global_load_lds(
                (const __attribute__((address_space(1))) void*)(Bt + (size_t)(n0 + row) * K + k0 + col),
                (__attribute__((address_space(3))) void*)(Bsm + ldsoff), 16, 0, 0);
        }
        __syncthreads();
        bf16x8 af[4], bfr[4];
#pragma unroll
        for (int mi = 0; mi < 4; mi++)
            af[mi] = *(const bf16x8*)(Asm + (wm * 64 + mi * 16 + r) * 32 + g * 8);
#pragma unroll
        for (int ni = 0; ni < 4; ni++)
            bfr[ni] = *(const bf16x8*)(Bsm + (wn * 64 + ni * 16 + r) * 32 + g * 8);
#pragma unroll
        for (int mi = 0; mi < 4; mi++)
#pragma unroll
            for (int ni = 0; ni < 4; ni++)
                acc[mi][ni] = __builtin_amdgcn_mfma_f32_16x16x32_bf16(af[mi], bfr[ni], acc[mi][ni], 0, 0, 0);
    }
#pragma unroll
    for (int mi = 0; mi < 4; mi++)
#pragma unroll
        for (int ni = 0; ni < 4; ni++) {
            int col = n0 + wn * 64 + ni * 16 + r;
            float bv = bias[col];
#pragma unroll
            for (int reg = 0; reg < 4; reg++) {
                int row = m0 + wm * 64 + mi * 16 + g * 4 + reg;
                float v = acc[mi][ni][reg] + bv;
                if (OUT_BF16)
                    ((ushort_t*)Cout)[(size_t)row * N + col] = f2bf(v);
                else
                    ((float*)Cout)[(size_t)row * N + col] = v;
            }
        }
}

// ---------------- RMSNorm + RoPE + scatter to head-major layouts ----------------
// qkv: [4096][3072] bf16.  Outputs: qh,kh: [32][2048][64] bf16 (q pre-scaled by 0.125),
// vT: [32][64][2048] bf16 (transposed for PV fragment loads).
__global__ __launch_bounds__(256) void norm_rope_k(const ushort_t* __restrict__ qkv,
                                                   const float* __restrict__ pe,
                                                   const float* __restrict__ qnw,
                                                   const float* __restrict__ knw,
                                                   ushort_t* __restrict__ qh,
                                                   ushort_t* __restrict__ kh,
                                                   ushort_t* __restrict__ vT) {
    int gtid = blockIdx.x * 256 + threadIdx.x;
    int d = gtid & 63;
    int vid = gtid >> 6;           // (m, t, h)
    int h = vid & 15;
    int t = (vid >> 4) % 3;
    int m = vid / 48;              // b*2048 + l
    int b = m >> 11, l = m & 2047;

    float val = bf2f(qkv[(size_t)m * 3072 + t * 1024 + h * 64 + d]);

    if (t == 2) {  // V: transpose-store
        vT[((size_t)(b * 16 + h) * 64 + d) * 2048 + l] = f2bf(val);
        return;
    }
    // RMS norm over 64 lanes
    float ss = val * val;
#pragma unroll
    for (int off = 1; off < 64; off <<= 1) ss += __shfl_xor(ss, off, 64);
    float rms = rsqrtf(ss * (1.0f / 64.0f) + EPSV);
    const float* nw = (t == 0) ? qnw : knw;
    float nv = val * rms * nw[d];
    // RoPE: pair (2p, 2p+1); pe flat index = l*128 + 2*d + {0,1}
    float partner = __shfl_xor(nv, 1, 64);
    int j = d & 1;
    float2 pv = *(const float2*)(pe + (size_t)l * 128 + 2 * d);
    float e0 = (j == 0) ? nv : partner;
    float e1 = (j == 0) ? partner : nv;
    float outv = pv.x * e0 + pv.y * e1;
    if (t == 0) outv *= 0.125f;  // fold in 1/sqrt(64)
    ushort_t* dst = (t == 0) ? qh : kh;
    dst[((size_t)(b * 16 + h) * 2048 + l) * 64 + d] = f2bf(outv);
}

// ---------------- Flash attention ----------------
// Grid: 32 (b*h) * 32 q-tiles-of-64 = 1024 blocks; 4 waves/block, each wave owns 16 q-rows.
__global__ __launch_bounds__(256) void attn_k(const ushort_t* __restrict__ qh,
                                              const ushort_t* __restrict__ kh,
                                              const ushort_t* __restrict__ vT,
                                              ushort_t* __restrict__ ob) {
    __shared__ __attribute__((aligned(16))) ushort_t Plds[4][16][72];  // +8 pad vs 64
    int tid = threadIdx.x;
    int lane = tid & 63, wid = tid >> 6;
    int r = lane & 15, g = lane >> 4;
    int bid = blockIdx.x;
    int bh = bid >> 5, qt = bid & 31;
    int q0 = qt * 64 + wid * 16;
    const ushort_t* Q  = qh + (size_t)bh * LL * 64;
    const ushort_t* Kb = kh + (size_t)bh * LL * 64;
    const ushort_t* Vt = vT + (size_t)bh * 64 * LL;

    // Q fragments (rows q0+r), hoisted for the whole KV loop
    bf16x8 qf0 = *(const bf16x8*)(Q + (size_t)(q0 + r) * 64 + g * 8);
    bf16x8 qf1 = *(const bf16x8*)(Q + (size_t)(q0 + r) * 64 + 32 + g * 8);

    f32x4 acc[4] = {};
    float mrow[4] = {-1e30f, -1e30f, -1e30f, -1e30f};
    float srow[4] = {0.f, 0.f, 0.f, 0.f};
    const f32x4 zero = {};

    for (int kvb = 0; kvb < LL; kvb += 64) {
        // QK^T: S[16 q][64 kv] in D-layout (row = g*4+reg, col = kt*16+r)
        f32x4 s[4];
#pragma unroll
        for (int kt = 0; kt < 4; kt++) {
            const ushort_t* kp = Kb + (size_t)(kvb + kt * 16 + r) * 64 + g * 8;
            bf16x8 k0 = *(const bf16x8*)(kp);
            bf16x8 k1 = *(const bf16x8*)(kp + 32);
            f32x4 tacc = __builtin_amdgcn_mfma_f32_16x16x32_bf16(qf0, k0, zero, 0, 0, 0);
            s[kt]      = __builtin_amdgcn_mfma_f32_16x16x32_bf16(qf1, k1, tacc, 0, 0, 0);
        }
        // online softmax update (per q-row = per reg, reduced over the 16-lane group)
        float alpha[4];
#pragma unroll
        for (int reg = 0; reg < 4; reg++) {
            float v = fmaxf(fmaxf(s[0][reg], s[1][reg]), fmaxf(s[2][reg], s[3][reg]));
            v = fmaxf(v, __shfl_xor(v, 1, 64));
            v = fmaxf(v, __shfl_xor(v, 2, 64));
            v = fmaxf(v, __shfl_xor(v, 4, 64));
            v = fmaxf(v, __shfl_xor(v, 8, 64));
            float mn = fmaxf(mrow[reg], v);
            alpha[reg] = __expf(mrow[reg] - mn);
            mrow[reg] = mn;
        }
#pragma unroll
        for (int reg = 0; reg < 4; reg++) {
            float rs = 0.f;
#pragma unroll
            for (int kt = 0; kt < 4; kt++) {
                float p = __expf(s[kt][reg] - mrow[reg]);
                s[kt][reg] = p;
                rs += p;
            }
            rs += __shfl_xor(rs, 1, 64);
            rs += __shfl_xor(rs, 2, 64);
            rs += __shfl_xor(rs, 4, 64);
            rs += __shfl_xor(rs, 8, 64);
            srow[reg] = srow[reg] * alpha[reg] + rs;
        }
#pragma unroll
        for (int dt = 0; dt < 4; dt++)
#pragma unroll
            for (int reg = 0; reg < 4; reg++) acc[dt][reg] *= alpha[reg];
        // P (bf16) -> LDS in A-layout-friendly form
#pragma unroll
        for (int kt = 0; kt < 4; kt++)
#pragma unroll
            for (int reg = 0; reg < 4; reg++)
                Plds[wid][g * 4 + reg][kt * 16 + r] = f2bf(s[kt][reg]);
        asm volatile("s_waitcnt lgkmcnt(0)" ::: "memory");
        bf16x8 pa0 = *(const bf16x8*)(&Plds[wid][r][g * 8]);
        bf16x8 pa1 = *(const bf16x8*)(&Plds[wid][r][32 + g * 8]);
        // PV: acc[dt] += P[16x64] * V[64 x 16*dt..]
#pragma unroll
        for (int dt = 0; dt < 4; dt++) {
            const ushort_t* vp = Vt + (size_t)(dt * 16 + r) * LL + kvb + g * 8;
            bf16x8 v0 = *(const bf16x8*)(vp);
            bf16x8 v1 = *(const bf16x8*)(vp + 32);
            acc[dt] = __builtin_amdgcn_mfma_f32_16x16x32_bf16(pa0, v0, acc[dt], 0, 0, 0);
            acc[dt] = __builtin_amdgcn_mfma_f32_16x16x32_bf16(pa1, v1, acc[dt], 0, 0, 0);
        }
    }
    // normalize + store to [B][L][H*D] bf16
    int b = bh >> 4, h = bh & 15;
#pragma unroll
    for (int dt = 0; dt < 4; dt++)
#pragma unroll
        for (int reg = 0; reg < 4; reg++) {
            int l = q0 + g * 4 + reg;
            ob[((size_t)(b * 2048 + l)) * 1024 + h * 64 + dt * 16 + r] =
                f2bf(acc[dt][reg] / srow[reg]);
        }
}

// ---------------- launcher ----------------
extern "C" void kernel_launch(void* const* d_in, const int* in_sizes, int n_in,
                              void* d_out, int out_size, void* d_ws, size_t ws_size,
                              hipStream_t stream) {
    const float* x      = (const float*)d_in[0];
    const float* pe     = (const float*)d_in[1];
    const float* qkv_w  = (const float*)d_in[2];
    const float* qkv_b  = (const float*)d_in[3];
    const float* qnw    = (const float*)d_in[4];
    const float* knw    = (const float*)d_in[5];
    const float* proj_w = (const float*)d_in[6];
    const float* proj_b = (const float*)d_in[7];
    float* out = (float*)d_out;

    char* ws = (char*)d_ws;
    // offsets (bytes)
    ushort_t* xb    = (ushort_t*)(ws);                         // 4096*1024*2 = 8 MB
    ushort_t* wqkv  = (ushort_t*)(ws + 8388608);               // 3072*1024*2 = 6 MB
    ushort_t* wproj = (ushort_t*)(ws + 8388608 + 6291456);     // 1024*1024*2 = 2 MB
    ushort_t* qkvb  = (ushort_t*)(ws + 16777216);              // 4096*3072*2 = 24 MB
    ushort_t* qhp   = (ushort_t*)(ws + 16777216 + 25165824);   // 8 MB
    ushort_t* khp   = (ushort_t*)(ws + 16777216 + 25165824 + 8388608);
    ushort_t* vtp   = (ushort_t*)(ws + 16777216 + 25165824 + 2 * 8388608);
    ushort_t* obp   = qkvb;  // reuse qkv region after norm_rope consumes it

    // converts
    f32_to_bf16_k<<<MTOT * DIM / 1024, 256, 0, stream>>>(x, xb, MTOT * DIM);
    f32_to_bf16_k<<<3 * DIM * DIM / 1024, 256, 0, stream>>>(qkv_w, wqkv, 3 * DIM * DIM);
    f32_to_bf16_k<<<DIM * DIM / 1024, 256, 0, stream>>>(proj_w, wproj, DIM * DIM);

    // QKV GEMM: [4096,1024] x [3072,1024]^T -> [4096,3072] bf16
    gemm_bt<1><<<dim3(3 * DIM / 128, MTOT / 128), 256, 0, stream>>>(xb, wqkv, qkv_b, qkvb,
                                                                    MTOT, 3 * DIM, DIM);
    // norm + rope + scatter
    norm_rope_k<<<MTOT * 3 * HEADS / 4, 256, 0, stream>>>(qkvb, pe, qnw, knw, qhp, khp, vtp);
    // attention
    attn_k<<<32 * 32, 256, 0, stream>>>(qhp, khp, vtp, obp);
    // output projection: [4096,1024] x [1024,1024]^T -> [4096,1024] fp32
    gemm_bt<0><<<dim3(DIM / 128, MTOT / 128), 256, 0, stream>>>(obp, wproj, proj_b, out,
                                                                MTOT, DIM, DIM);
}

// Round 2
// 260.100 us; speedup vs baseline: 1.8059x; 1.8059x over previous
//
#include <hip/hip_runtime.h>
#include <hip/hip_bf16.h>

#define DIM   1024
#define HEADS 16
#define HD    64
#define BB    2
#define LL    2048
#define MTOT  (BB*LL)   // 4096
#define EPSV  1.1920928955078125e-07f

typedef __attribute__((ext_vector_type(8))) short bf16x8;
typedef __attribute__((ext_vector_type(4))) float f32x4;
typedef unsigned short ushort_t;

__device__ __forceinline__ float bf2f(ushort_t u) {
    unsigned int x = ((unsigned int)u) << 16;
    return __builtin_bit_cast(float, x);
}
__device__ __forceinline__ ushort_t f2bf(float f) {
    unsigned int x = __builtin_bit_cast(unsigned int, f);
    unsigned int r = (x + 0x7FFFu + ((x >> 16) & 1u)) >> 16;
    return (ushort_t)r;
}

// ---------------- fp32 -> bf16 convert (vectorized) ----------------
__global__ __launch_bounds__(256) void f32_to_bf16_k(const float* __restrict__ in,
                                                     ushort_t* __restrict__ out, int n) {
    int i = (blockIdx.x * 256 + threadIdx.x) * 4;
    if (i < n) {
        float4 v = *(const float4*)(in + i);
        ushort4 o;
        o.x = f2bf(v.x); o.y = f2bf(v.y); o.z = f2bf(v.z); o.w = f2bf(v.w);
        *(ushort4*)(out + i) = o;
    }
}

// ---------------- GEMM: C[M][N] = A[M][K] * Bt[N][K]^T + bias ----------------
template <int OUT_BF16>
__global__ __launch_bounds__(256) void gemm_bt(const ushort_t* __restrict__ A,
                                               const ushort_t* __restrict__ Bt,
                                               const float* __restrict__ bias,
                                               void* __restrict__ Cout,
                                               int M, int N, int K) {
    __shared__ __attribute__((aligned(16))) ushort_t Asm[128 * 32];
    __shared__ __attribute__((aligned(16))) ushort_t Bsm[128 * 32];
    int tid = threadIdx.x;
    int lane = tid & 63, wid = tid >> 6;
    int wm = wid >> 1, wn = wid & 1;
    int r = lane & 15, g = lane >> 4;
    int m0 = blockIdx.y * 128, n0 = blockIdx.x * 128;

    f32x4 acc[4][4] = {};

    int niter = K >> 5;
    for (int kk = 0; kk < niter; ++kk) {
        int k0 = kk << 5;
        __syncthreads();
#pragma unroll
        for (int p = 0; p < 2; ++p) {
            int off = (p * 256 + tid) * 8;
            int row = off >> 5, col = off & 31;
            int ldsoff = (p * 256 + wid * 64) * 8;
            __builtin_amdgcn_global_load_lds(
                (const __attribute__((address_space(1))) void*)(A + (size_t)(m0 + row) * K + k0 + col),
                (__attribute__((address_space(3))) void*)(Asm + ldsoff), 16, 0, 0);
            __builtin_amdgcn_global_load_lds(
                (const __attribute__((address_space(1))) void*)(Bt + (size_t)(n0 + row) * K + k0 + col),
                (__attribute__((address_space(3))) void*)(Bsm + ldsoff), 16, 0, 0);
        }
        __syncthreads();
        bf16x8 af[4], bfr[4];
#pragma unroll
        for (int mi = 0; mi < 4; mi++)
            af[mi] = *(const bf16x8*)(Asm + (wm * 64 + mi * 16 + r) * 32 + g * 8);
#pragma unroll
        for (int ni = 0; ni < 4; ni++)
            bfr[ni] = *(const bf16x8*)(Bsm + (wn * 64 + ni * 16 + r) * 32 + g * 8);
#pragma unroll
        for (int mi = 0; mi < 4; mi++)
#pragma unroll
            for (int ni = 0; ni < 4; ni++)
                acc[mi][ni] = __builtin_amdgcn_mfma_f32_16x16x32_bf16(af[mi], bfr[ni], acc[mi][ni], 0, 0, 0);
    }
#pragma unroll
    for (int mi = 0; mi < 4; mi++)
#pragma unroll
        for (int ni = 0; ni < 4; ni++) {
            int col = n0 + wn * 64 + ni * 16 + r;
            float bv = bias[col];
#pragma unroll
            for (int reg = 0; reg < 4; reg++) {
                int row = m0 + wm * 64 + mi * 16 + g * 4 + reg;
                float v = acc[mi][ni][reg] + bv;
                if (OUT_BF16)
                    ((ushort_t*)Cout)[(size_t)row * N + col] = f2bf(v);
                else
                    ((float*)Cout)[(size_t)row * N + col] = v;
            }
        }
}

// ---------------- RMSNorm + RoPE + scatter to head-major layouts ----------------
__global__ __launch_bounds__(256) void norm_rope_k(const ushort_t* __restrict__ qkv,
                                                   const float* __restrict__ pe,
                                                   const float* __restrict__ qnw,
                                                   const float* __restrict__ knw,
                                                   ushort_t* __restrict__ qh,
                                                   ushort_t* __restrict__ kh,
                                                   ushort_t* __restrict__ vT) {
    int gtid = blockIdx.x * 256 + threadIdx.x;
    int d = gtid & 63;
    int vid = gtid >> 6;
    int h = vid & 15;
    int t = (vid >> 4) % 3;
    int m = vid / 48;
    int b = m >> 11, l = m & 2047;

    float val = bf2f(qkv[(size_t)m * 3072 + t * 1024 + h * 64 + d]);

    if (t == 2) {
        vT[((size_t)(b * 16 + h) * 64 + d) * 2048 + l] = f2bf(val);
        return;
    }
    float ss = val * val;
#pragma unroll
    for (int off = 1; off < 64; off <<= 1) ss += __shfl_xor(ss, off, 64);
    float rms = rsqrtf(ss * (1.0f / 64.0f) + EPSV);
    const float* nw = (t == 0) ? qnw : knw;
    float nv = val * rms * nw[d];
    float partner = __shfl_xor(nv, 1, 64);
    int j = d & 1;
    float2 pv = *(const float2*)(pe + (size_t)l * 128 + 2 * d);
    float e0 = (j == 0) ? nv : partner;
    float e1 = (j == 0) ? partner : nv;
    float outv = pv.x * e0 + pv.y * e1;
    if (t == 0) outv *= 0.125f;
    ushort_t* dst = (t == 0) ? qh : kh;
    dst[((size_t)(b * 16 + h) * 2048 + l) * 64 + d] = f2bf(outv);
}

// ---------------- Flash attention v2 ----------------
// Grid: (16 q-tiles, 32 bh). Block = 4 waves x 32 q-rows = 128 q-rows.
// K,V staged in LDS (double-buffered, XOR-swizzled via pre-swizzled global src).
// Swapped QK^T: s = mfma(K,Q) -> per-lane softmax stats (q = lane&15).
__global__ __launch_bounds__(256, 2) void attn_k(const ushort_t* __restrict__ qh,
                                                 const ushort_t* __restrict__ kh,
                                                 const ushort_t* __restrict__ vT,
                                                 ushort_t* __restrict__ ob) {
    __shared__ __attribute__((aligned(16))) ushort_t Ksm[2][64 * 64];
    __shared__ __attribute__((aligned(16))) ushort_t Vsm[2][64 * 64];
    __shared__ __attribute__((aligned(16))) ushort_t Plds[4][2][16 * 64];

    const int tid = threadIdx.x;
    const int lane = tid & 63, wid = tid >> 6;
    const int r = lane & 15, g = lane >> 4;
    const int qt = blockIdx.x, bh = blockIdx.y;
    const int q0 = qt * 128 + wid * 32;
    const ushort_t* Q  = qh + (size_t)bh * LL * 64;
    const ushort_t* Kb = kh + (size_t)bh * LL * 64;
    const ushort_t* Vt = vT + (size_t)bh * 64 * LL;

    // staging constants: chunk c = q*256+tid; logical (row, cc) with cc pre-swizzled
    int row_[2], ccx_[2];
#pragma unroll
    for (int q = 0; q < 2; ++q) {
        int c = q * 256 + tid;
        row_[q] = c >> 3;
        ccx_[q] = (c & 7) ^ (row_[q] & 7);
    }
    const int swz = (r & 7) * 8;  // read-side XOR key (ushort units; granule = 8 ushorts)

    // Q fragments (held all loop): B-operand rows q = q0 + mf*16 + r
    bf16x8 qf[2][2];
#pragma unroll
    for (int mf = 0; mf < 2; ++mf)
#pragma unroll
        for (int hf = 0; hf < 2; ++hf)
            qf[mf][hf] = *(const bf16x8*)(Q + (size_t)(q0 + mf * 16 + r) * 64 + hf * 32 + g * 8);

    f32x4 acc[2][4] = {};
    float mrow[2] = {-1e30f, -1e30f};
    float srow[2] = {0.f, 0.f};
    const f32x4 zero = {};

    // prologue stage into buf 0
#pragma unroll
    for (int q = 0; q < 2; ++q) {
        __builtin_amdgcn_global_load_lds(
            (const __attribute__((address_space(1))) void*)(Kb + (size_t)row_[q] * 64 + ccx_[q] * 8),
            (__attribute__((address_space(3))) void*)(&Ksm[0][0] + (q * 256 + wid * 64) * 8), 16, 0, 0);
        __builtin_amdgcn_global_load_lds(
            (const __attribute__((address_space(1))) void*)(Vt + (size_t)row_[q] * 2048 + ccx_[q] * 8),
            (__attribute__((address_space(3))) void*)(&Vsm[0][0] + (q * 256 + wid * 64) * 8), 16, 0, 0);
    }
    __syncthreads();

    int buf = 0;
    for (int it = 0; it < 32; ++it) {
        // stage next tile into the other buffer (T3-minimal 2-phase)
        if (it < 31) {
            int kvn = (it + 1) * 64;
#pragma unroll
            for (int q = 0; q < 2; ++q) {
                __builtin_amdgcn_global_load_lds(
                    (const __attribute__((address_space(1))) void*)(Kb + (size_t)(kvn + row_[q]) * 64 + ccx_[q] * 8),
                    (__attribute__((address_space(3))) void*)(&Ksm[buf ^ 1][0] + (q * 256 + wid * 64) * 8), 16, 0, 0);
                __builtin_amdgcn_global_load_lds(
                    (const __attribute__((address_space(1))) void*)(Vt + (size_t)row_[q] * 2048 + kvn + ccx_[q] * 8),
                    (__attribute__((address_space(3))) void*)(&Vsm[buf ^ 1][0] + (q * 256 + wid * 64) * 8), 16, 0, 0);
            }
        }
        const ushort_t* Kl = &Ksm[buf][0];
        const ushort_t* Vl = &Vsm[buf][0];

        // K fragments (A-operand rows kv = kt*16 + r), reused by both mf
        bf16x8 kf[4][2];
#pragma unroll
        for (int kt = 0; kt < 4; ++kt)
#pragma unroll
            for (int hf = 0; hf < 2; ++hf)
                kf[kt][hf] = *(const bf16x8*)(Kl + (kt * 16 + r) * 64 + (((hf * 4 + g) * 8) ^ swz));

        // QK^T (swapped): D[kv][q], q = lane&15, kv = kt*16 + g*4 + reg
        f32x4 s[2][4];
        __builtin_amdgcn_s_setprio(1);
#pragma unroll
        for (int mf = 0; mf < 2; ++mf)
#pragma unroll
            for (int kt = 0; kt < 4; ++kt) {
                f32x4 t0 = __builtin_amdgcn_mfma_f32_16x16x32_bf16(kf[kt][0], qf[mf][0], zero, 0, 0, 0);
                s[mf][kt] = __builtin_amdgcn_mfma_f32_16x16x32_bf16(kf[kt][1], qf[mf][1], t0, 0, 0, 0);
            }
        __builtin_amdgcn_s_setprio(0);

        // online softmax (per-lane: q = r), P -> LDS (bf16, swizzled)
#pragma unroll
        for (int mf = 0; mf < 2; ++mf) {
            float pm = -1e30f;
#pragma unroll
            for (int kt = 0; kt < 4; ++kt)
#pragma unroll
                for (int reg = 0; reg < 4; ++reg) pm = fmaxf(pm, s[mf][kt][reg]);
            pm = fmaxf(pm, __shfl_xor(pm, 16, 64));
            pm = fmaxf(pm, __shfl_xor(pm, 32, 64));
            float mn = fmaxf(mrow[mf], pm);
            float al = __expf(mrow[mf] - mn);
            mrow[mf] = mn;
            float rs = 0.f;
#pragma unroll
            for (int kt = 0; kt < 4; ++kt)
#pragma unroll
                for (int reg = 0; reg < 4; ++reg) {
                    float p = __expf(s[mf][kt][reg] - mn);
                    s[mf][kt][reg] = p;
                    rs += p;
                }
            rs += __shfl_xor(rs, 16, 64);
            rs += __shfl_xor(rs, 32, 64);
            srow[mf] = srow[mf] * al + rs;
            // broadcast alpha from lane (q = g*4+reg) and rescale acc
            float ab[4];
#pragma unroll
            for (int reg = 0; reg < 4; ++reg) ab[reg] = __shfl(al, g * 4 + reg, 16);
#pragma unroll
            for (int dt = 0; dt < 4; ++dt)
#pragma unroll
                for (int reg = 0; reg < 4; ++reg) acc[mf][dt][reg] *= ab[reg];
            // P write: row q=r, kv cols kt*16+g*4 .. +3 (b64), swizzled like K/V
#pragma unroll
            for (int kt = 0; kt < 4; ++kt) {
                ushort4 pw;
                pw.x = f2bf(s[mf][kt][0]); pw.y = f2bf(s[mf][kt][1]);
                pw.z = f2bf(s[mf][kt][2]); pw.w = f2bf(s[mf][kt][3]);
                *(ushort4*)(&Plds[wid][mf][0] + r * 64 + (((2 * kt + (g >> 1)) * 8) ^ swz) + (g & 1) * 4) = pw;
            }
        }
        asm volatile("s_waitcnt lgkmcnt(0)" ::: "memory");
        __builtin_amdgcn_sched_barrier(0);

        bf16x8 pa[2][2];
#pragma unroll
        for (int mf = 0; mf < 2; ++mf)
#pragma unroll
            for (int hf = 0; hf < 2; ++hf)
                pa[mf][hf] = *(const bf16x8*)(&Plds[wid][mf][0] + r * 64 + (((hf * 4 + g) * 8) ^ swz));

        // PV: acc[mf][dt] += P[q][kv] * V[kv][d]
        __builtin_amdgcn_s_setprio(1);
#pragma unroll
        for (int dt = 0; dt < 4; ++dt)
#pragma unroll
            for (int hv = 0; hv < 2; ++hv) {
                bf16x8 vf = *(const bf16x8*)(Vl + (dt * 16 + r) * 64 + (((hv * 4 + g) * 8) ^ swz));
#pragma unroll
                for (int mf = 0; mf < 2; ++mf)
                    acc[mf][dt] = __builtin_amdgcn_mfma_f32_16x16x32_bf16(pa[mf][hv], vf, acc[mf][dt], 0, 0, 0);
            }
        __builtin_amdgcn_s_setprio(0);

        __syncthreads();  // drains vmcnt (next-tile stage) + lgkmcnt, guards buffer swap
        buf ^= 1;
    }

    // epilogue: normalize + store [B][L][H*D]
    int b = bh >> 4, h = bh & 15;
#pragma unroll
    for (int mf = 0; mf < 2; ++mf) {
        float sinv = 1.0f / srow[mf];
        float sb[4];
#pragma unroll
        for (int reg = 0; reg < 4; ++reg) sb[reg] = __shfl(sinv, g * 4 + reg, 16);
#pragma unroll
        for (int dt = 0; dt < 4; ++dt)
#pragma unroll
            for (int reg = 0; reg < 4; ++reg) {
                int l = q0 + mf * 16 + g * 4 + reg;
                ob[((size_t)(b * 2048 + l)) * 1024 + h * 64 + dt * 16 + r] =
                    f2bf(acc[mf][dt][reg] * sb[reg]);
            }
    }
}

// ---------------- launcher ----------------
extern "C" void kernel_launch(void* const* d_in, const int* in_sizes, int n_in,
                              void* d_out, int out_size, void* d_ws, size_t ws_size,
                              hipStream_t stream) {
    const float* x      = (const float*)d_in[0];
    const float* pe     = (const float*)d_in[1];
    const float* qkv_w  = (const float*)d_in[2];
    const float* qkv_b  = (const float*)d_in[3];
    const float* qnw    = (const float*)d_in[4];
    const float* knw    = (const float*)d_in[5];
    const float* proj_w = (const float*)d_in[6];
    const float* proj_b = (const float*)d_in[7];
    float* out = (float*)d_out;

    char* ws = (char*)d_ws;
    ushort_t* xb    = (ushort_t*)(ws);                         // 8 MB
    ushort_t* wqkv  = (ushort_t*)(ws + 8388608);               // 6 MB
    ushort_t* wproj = (ushort_t*)(ws + 8388608 + 6291456);     // 2 MB
    ushort_t* qkvb  = (ushort_t*)(ws + 16777216);              // 24 MB
    ushort_t* qhp   = (ushort_t*)(ws + 16777216 + 25165824);   // 8 MB
    ushort_t* khp   = (ushort_t*)(ws + 16777216 + 25165824 + 8388608);
    ushort_t* vtp   = (ushort_t*)(ws + 16777216 + 25165824 + 2 * 8388608);
    ushort_t* obp   = qkvb;  // reuse qkv region

    f32_to_bf16_k<<<MTOT * DIM / 1024, 256, 0, stream>>>(x, xb, MTOT * DIM);
    f32_to_bf16_k<<<3 * DIM * DIM / 1024, 256, 0, stream>>>(qkv_w, wqkv, 3 * DIM * DIM);
    f32_to_bf16_k<<<DIM * DIM / 1024, 256, 0, stream>>>(proj_w, wproj, DIM * DIM);

    gemm_bt<1><<<dim3(3 * DIM / 128, MTOT / 128), 256, 0, stream>>>(xb, wqkv, qkv_b, qkvb,
                                                                    MTOT, 3 * DIM, DIM);
    norm_rope_k<<<MTOT * 3 * HEADS / 4, 256, 0, stream>>>(qkvb, pe, qnw, knw, qhp, khp, vtp);
    attn_k<<<dim3(16, 32), 256, 0, stream>>>(qhp, khp, vtp, obp);
    gemm_bt<0><<<dim3(DIM / 128, MTOT / 128), 256, 0, stream>>>(obp, wproj, proj_b, out,
                                                                MTOT, DIM, DIM);
}

// Round 3
// 232.717 us; speedup vs baseline: 2.0184x; 1.1177x over previous
//
#include <hip/hip_runtime.h>
#include <hip/hip_bf16.h>

#define DIM   1024
#define HEADS 16
#define HD    64
#define BB    2
#define LL    2048
#define MTOT  (BB*LL)   // 4096
#define EPSV  1.1920928955078125e-07f

typedef __attribute__((ext_vector_type(8))) short bf16x8;
typedef __attribute__((ext_vector_type(4))) float f32x4;
typedef unsigned short ushort_t;

__device__ __forceinline__ float bf2f(ushort_t u) {
    unsigned int x = ((unsigned int)u) << 16;
    return __builtin_bit_cast(float, x);
}
__device__ __forceinline__ ushort_t f2bf(float f) {
    unsigned int x = __builtin_bit_cast(unsigned int, f);
    unsigned int r = (x + 0x7FFFu + ((x >> 16) & 1u)) >> 16;
    return (ushort_t)r;
}

// ---------------- fp32 -> bf16 convert (vectorized) ----------------
__global__ __launch_bounds__(256) void f32_to_bf16_k(const float* __restrict__ in,
                                                     ushort_t* __restrict__ out, int n) {
    int i = (blockIdx.x * 256 + threadIdx.x) * 4;
    if (i < n) {
        float4 v = *(const float4*)(in + i);
        ushort4 o;
        o.x = f2bf(v.x); o.y = f2bf(v.y); o.z = f2bf(v.z); o.w = f2bf(v.w);
        *(ushort4*)(out + i) = o;
    }
}

// ---------------- GEMM: C[M][N] = A[M][K] * Bt[N][K]^T + bias ----------------
template <int OUT_BF16>
__global__ __launch_bounds__(256) void gemm_bt(const ushort_t* __restrict__ A,
                                               const ushort_t* __restrict__ Bt,
                                               const float* __restrict__ bias,
                                               void* __restrict__ Cout,
                                               int M, int N, int K) {
    __shared__ __attribute__((aligned(16))) ushort_t Asm[128 * 32];
    __shared__ __attribute__((aligned(16))) ushort_t Bsm[128 * 32];
    int tid = threadIdx.x;
    int lane = tid & 63, wid = tid >> 6;
    int wm = wid >> 1, wn = wid & 1;
    int r = lane & 15, g = lane >> 4;
    int m0 = blockIdx.y * 128, n0 = blockIdx.x * 128;

    f32x4 acc[4][4] = {};

    int niter = K >> 5;
    for (int kk = 0; kk < niter; ++kk) {
        int k0 = kk << 5;
        __syncthreads();
#pragma unroll
        for (int p = 0; p < 2; ++p) {
            int off = (p * 256 + tid) * 8;
            int row = off >> 5, col = off & 31;
            int ldsoff = (p * 256 + wid * 64) * 8;
            __builtin_amdgcn_global_load_lds(
                (const __attribute__((address_space(1))) void*)(A + (size_t)(m0 + row) * K + k0 + col),
                (__attribute__((address_space(3))) void*)(Asm + ldsoff), 16, 0, 0);
            __builtin_amdgcn_global_load_lds(
                (const __attribute__((address_space(1))) void*)(Bt + (size_t)(n0 + row) * K + k0 + col),
                (__attribute__((address_space(3))) void*)(Bsm + ldsoff), 16, 0, 0);
        }
        __syncthreads();
        bf16x8 af[4], bfr[4];
#pragma unroll
        for (int mi = 0; mi < 4; mi++)
            af[mi] = *(const bf16x8*)(Asm + (wm * 64 + mi * 16 + r) * 32 + g * 8);
#pragma unroll
        for (int ni = 0; ni < 4; ni++)
            bfr[ni] = *(const bf16x8*)(Bsm + (wn * 64 + ni * 16 + r) * 32 + g * 8);
#pragma unroll
        for (int mi = 0; mi < 4; mi++)
#pragma unroll
            for (int ni = 0; ni < 4; ni++)
                acc[mi][ni] = __builtin_amdgcn_mfma_f32_16x16x32_bf16(af[mi], bfr[ni], acc[mi][ni], 0, 0, 0);
    }
#pragma unroll
    for (int mi = 0; mi < 4; mi++)
#pragma unroll
        for (int ni = 0; ni < 4; ni++) {
            int col = n0 + wn * 64 + ni * 16 + r;
            float bv = bias[col];
#pragma unroll
            for (int reg = 0; reg < 4; reg++) {
                int row = m0 + wm * 64 + mi * 16 + g * 4 + reg;
                float v = acc[mi][ni][reg] + bv;
                if (OUT_BF16)
                    ((ushort_t*)Cout)[(size_t)row * N + col] = f2bf(v);
                else
                    ((float*)Cout)[(size_t)row * N + col] = v;
            }
        }
}

// ---------------- RMSNorm + RoPE + scatter (vectorized, coalesced V-transpose) ---
// Grid: (32 l-tiles, 3 t, 32 bh), 256 threads. Each block: 64 l x 64 d of one (t,b,h).
// Lane owns 4 consecutive d -> ushort4/float4 loads; RoPE pairs in-lane.
// V: LDS 64x68 tile transpose -> coalesced 128B row writes into vT.
__global__ __launch_bounds__(256) void norm_rope_k(const ushort_t* __restrict__ qkv,
                                                   const float* __restrict__ pe,
                                                   const float* __restrict__ qnw,
                                                   const float* __restrict__ knw,
                                                   ushort_t* __restrict__ qh,
                                                   ushort_t* __restrict__ kh,
                                                   ushort_t* __restrict__ vT) {
    __shared__ ushort_t T[64][68];
    const int tid = threadIdx.x;
    const int lane = tid & 63, w = tid >> 6;
    const int rg = lane >> 4;
    const int d4 = (lane & 15) * 4;
    const int l0 = blockIdx.x * 64;
    const int t  = blockIdx.y;
    const int bh = blockIdx.z;
    const int b = bh >> 4, h = bh & 15;

    if (t == 2) {  // V: bf16 copy + transpose through LDS
#pragma unroll
        for (int i = 0; i < 4; ++i) {
            int ll = w * 16 + rg + 4 * i;
            int m = b * 2048 + l0 + ll;
            ushort4 v = *(const ushort4*)(qkv + (size_t)m * 3072 + 2048 + h * 64 + d4);
            *(ushort4*)(&T[ll][d4]) = v;
        }
        __syncthreads();
        const int d = tid >> 2, lq = (tid & 3) * 16;
        ushort_t* dst = vT + ((size_t)(bh * 64 + d)) * 2048 + l0 + lq;
#pragma unroll
        for (int c = 0; c < 4; ++c) {
            ushort4 o;
            o.x = T[lq + c * 4 + 0][d];
            o.y = T[lq + c * 4 + 1][d];
            o.z = T[lq + c * 4 + 2][d];
            o.w = T[lq + c * 4 + 3][d];
            *(ushort4*)(dst + c * 4) = o;
        }
        return;
    }

    const float* nwp = (t == 0) ? qnw : knw;
    const float4 nwv = *(const float4*)(nwp + d4);
    ushort_t* dst = (t == 0) ? qh : kh;
    const float qscale = (t == 0) ? 0.125f : 1.0f;
#pragma unroll
    for (int i = 0; i < 4; ++i) {
        int ll = w * 16 + rg + 4 * i;
        int l = l0 + ll;
        int m = b * 2048 + l;
        ushort4 vv = *(const ushort4*)(qkv + (size_t)m * 3072 + t * 1024 + h * 64 + d4);
        float v0 = bf2f(vv.x), v1 = bf2f(vv.y), v2 = bf2f(vv.z), v3 = bf2f(vv.w);
        float ss = v0 * v0 + v1 * v1 + v2 * v2 + v3 * v3;
        ss += __shfl_xor(ss, 1, 64);
        ss += __shfl_xor(ss, 2, 64);
        ss += __shfl_xor(ss, 4, 64);
        ss += __shfl_xor(ss, 8, 64);
        float rms = rsqrtf(ss * (1.0f / 64.0f) + EPSV);
        v0 *= rms * nwv.x; v1 *= rms * nwv.y; v2 *= rms * nwv.z; v3 *= rms * nwv.w;
        float4 p0 = *(const float4*)(pe + (size_t)l * 128 + 2 * d4);
        float4 p1 = *(const float4*)(pe + (size_t)l * 128 + 2 * d4 + 4);
        float o0 = (p0.x * v0 + p0.y * v1) * qscale;
        float o1 = (p0.z * v0 + p0.w * v1) * qscale;
        float o2 = (p1.x * v2 + p1.y * v3) * qscale;
        float o3 = (p1.z * v2 + p1.w * v3) * qscale;
        ushort4 o;
        o.x = f2bf(o0); o.y = f2bf(o1); o.z = f2bf(o2); o.w = f2bf(o3);
        *(ushort4*)(dst + ((size_t)bh * 2048 + l) * 64 + d4) = o;
    }
}

// ---------------- Flash attention v2 + defer-max (T13) ----------------
__global__ __launch_bounds__(256, 2) void attn_k(const ushort_t* __restrict__ qh,
                                                 const ushort_t* __restrict__ kh,
                                                 const ushort_t* __restrict__ vT,
                                                 ushort_t* __restrict__ ob) {
    __shared__ __attribute__((aligned(16))) ushort_t Ksm[2][64 * 64];
    __shared__ __attribute__((aligned(16))) ushort_t Vsm[2][64 * 64];
    __shared__ __attribute__((aligned(16))) ushort_t Plds[4][2][16 * 64];

    const int tid = threadIdx.x;
    const int lane = tid & 63, wid = tid >> 6;
    const int r = lane & 15, g = lane >> 4;
    const int qt = blockIdx.x, bh = blockIdx.y;
    const int q0 = qt * 128 + wid * 32;
    const ushort_t* Q  = qh + (size_t)bh * LL * 64;
    const ushort_t* Kb = kh + (size_t)bh * LL * 64;
    const ushort_t* Vt = vT + (size_t)bh * 64 * LL;

    int row_[2], ccx_[2];
#pragma unroll
    for (int q = 0; q < 2; ++q) {
        int c = q * 256 + tid;
        row_[q] = c >> 3;
        ccx_[q] = (c & 7) ^ (row_[q] & 7);
    }
    const int swz = (r & 7) * 8;

    bf16x8 qf[2][2];
#pragma unroll
    for (int mf = 0; mf < 2; ++mf)
#pragma unroll
        for (int hf = 0; hf < 2; ++hf)
            qf[mf][hf] = *(const bf16x8*)(Q + (size_t)(q0 + mf * 16 + r) * 64 + hf * 32 + g * 8);

    f32x4 acc[2][4] = {};
    float mrow[2] = {-1e30f, -1e30f};
    float srow[2] = {0.f, 0.f};
    const f32x4 zero = {};

#pragma unroll
    for (int q = 0; q < 2; ++q) {
        __builtin_amdgcn_global_load_lds(
            (const __attribute__((address_space(1))) void*)(Kb + (size_t)row_[q] * 64 + ccx_[q] * 8),
            (__attribute__((address_space(3))) void*)(&Ksm[0][0] + (q * 256 + wid * 64) * 8), 16, 0, 0);
        __builtin_amdgcn_global_load_lds(
            (const __attribute__((address_space(1))) void*)(Vt + (size_t)row_[q] * 2048 + ccx_[q] * 8),
            (__attribute__((address_space(3))) void*)(&Vsm[0][0] + (q * 256 + wid * 64) * 8), 16, 0, 0);
    }
    __syncthreads();

    int buf = 0;
    for (int it = 0; it < 32; ++it) {
        if (it < 31) {
            int kvn = (it + 1) * 64;
#pragma unroll
            for (int q = 0; q < 2; ++q) {
                __builtin_amdgcn_global_load_lds(
                    (const __attribute__((address_space(1))) void*)(Kb + (size_t)(kvn + row_[q]) * 64 + ccx_[q] * 8),
                    (__attribute__((address_space(3))) void*)(&Ksm[buf ^ 1][0] + (q * 256 + wid * 64) * 8), 16, 0, 0);
                __builtin_amdgcn_global_load_lds(
                    (const __attribute__((address_space(1))) void*)(Vt + (size_t)row_[q] * 2048 + kvn + ccx_[q] * 8),
                    (__attribute__((address_space(3))) void*)(&Vsm[buf ^ 1][0] + (q * 256 + wid * 64) * 8), 16, 0, 0);
            }
        }
        const ushort_t* Kl = &Ksm[buf][0];
        const ushort_t* Vl = &Vsm[buf][0];

        bf16x8 kf[4][2];
#pragma unroll
        for (int kt = 0; kt < 4; ++kt)
#pragma unroll
            for (int hf = 0; hf < 2; ++hf)
                kf[kt][hf] = *(const bf16x8*)(Kl + (kt * 16 + r) * 64 + (((hf * 4 + g) * 8) ^ swz));

        f32x4 s[2][4];
        __builtin_amdgcn_s_setprio(1);
#pragma unroll
        for (int mf = 0; mf < 2; ++mf)
#pragma unroll
            for (int kt = 0; kt < 4; ++kt) {
                f32x4 t0 = __builtin_amdgcn_mfma_f32_16x16x32_bf16(kf[kt][0], qf[mf][0], zero, 0, 0, 0);
                s[mf][kt] = __builtin_amdgcn_mfma_f32_16x16x32_bf16(kf[kt][1], qf[mf][1], t0, 0, 0, 0);
            }
        __builtin_amdgcn_s_setprio(0);

#pragma unroll
        for (int mf = 0; mf < 2; ++mf) {
            float pm = -1e30f;
#pragma unroll
            for (int kt = 0; kt < 4; ++kt)
#pragma unroll
                for (int reg = 0; reg < 4; ++reg) pm = fmaxf(pm, s[mf][kt][reg]);
            pm = fmaxf(pm, __shfl_xor(pm, 16, 64));
            pm = fmaxf(pm, __shfl_xor(pm, 32, 64));
            // T13 defer-max: skip rescale while tile max stays within THR of running max
            bool skip = (__all(pm <= mrow[mf] + 8.0f) != 0);
            float mn, al;
            if (skip) {
                mn = mrow[mf];
            } else {
                mn = fmaxf(mrow[mf], pm);
                al = __expf(mrow[mf] - mn);
                mrow[mf] = mn;
            }
            float rs = 0.f;
#pragma unroll
            for (int kt = 0; kt < 4; ++kt)
#pragma unroll
                for (int reg = 0; reg < 4; ++reg) {
                    float p = __expf(s[mf][kt][reg] - mn);
                    s[mf][kt][reg] = p;
                    rs += p;
                }
            rs += __shfl_xor(rs, 16, 64);
            rs += __shfl_xor(rs, 32, 64);
            if (skip) {
                srow[mf] += rs;
            } else {
                srow[mf] = srow[mf] * al + rs;
                float ab[4];
#pragma unroll
                for (int reg = 0; reg < 4; ++reg) ab[reg] = __shfl(al, g * 4 + reg, 16);
#pragma unroll
                for (int dt = 0; dt < 4; ++dt)
#pragma unroll
                    for (int reg = 0; reg < 4; ++reg) acc[mf][dt][reg] *= ab[reg];
            }
#pragma unroll
            for (int kt = 0; kt < 4; ++kt) {
                ushort4 pw;
                pw.x = f2bf(s[mf][kt][0]); pw.y = f2bf(s[mf][kt][1]);
                pw.z = f2bf(s[mf][kt][2]); pw.w = f2bf(s[mf][kt][3]);
                *(ushort4*)(&Plds[wid][mf][0] + r * 64 + (((2 * kt + (g >> 1)) * 8) ^ swz) + (g & 1) * 4) = pw;
            }
        }
        asm volatile("s_waitcnt lgkmcnt(0)" ::: "memory");
        __builtin_amdgcn_sched_barrier(0);

        bf16x8 pa[2][2];
#pragma unroll
        for (int mf = 0; mf < 2; ++mf)
#pragma unroll
            for (int hf = 0; hf < 2; ++hf)
                pa[mf][hf] = *(const bf16x8*)(&Plds[wid][mf][0] + r * 64 + (((hf * 4 + g) * 8) ^ swz));

        __builtin_amdgcn_s_setprio(1);
#pragma unroll
        for (int dt = 0; dt < 4; ++dt)
#pragma unroll
            for (int hv = 0; hv < 2; ++hv) {
                bf16x8 vf = *(const bf16x8*)(Vl + (dt * 16 + r) * 64 + (((hv * 4 + g) * 8) ^ swz));
#pragma unroll
                for (int mf = 0; mf < 2; ++mf)
                    acc[mf][dt] = __builtin_amdgcn_mfma_f32_16x16x32_bf16(pa[mf][hv], vf, acc[mf][dt], 0, 0, 0);
            }
        __builtin_amdgcn_s_setprio(0);

        __syncthreads();
        buf ^= 1;
    }

    int b = bh >> 4, h = bh & 15;
#pragma unroll
    for (int mf = 0; mf < 2; ++mf) {
        float sinv = 1.0f / srow[mf];
        float sb[4];
#pragma unroll
        for (int reg = 0; reg < 4; ++reg) sb[reg] = __shfl(sinv, g * 4 + reg, 16);
#pragma unroll
        for (int dt = 0; dt < 4; ++dt)
#pragma unroll
            for (int reg = 0; reg < 4; ++reg) {
                int l = q0 + mf * 16 + g * 4 + reg;
                ob[((size_t)(b * 2048 + l)) * 1024 + h * 64 + dt * 16 + r] =
                    f2bf(acc[mf][dt][reg] * sb[reg]);
            }
    }
}

// ---------------- launcher ----------------
extern "C" void kernel_launch(void* const* d_in, const int* in_sizes, int n_in,
                              void* d_out, int out_size, void* d_ws, size_t ws_size,
                              hipStream_t stream) {
    const float* x      = (const float*)d_in[0];
    const float* pe     = (const float*)d_in[1];
    const float* qkv_w  = (const float*)d_in[2];
    const float* qkv_b  = (const float*)d_in[3];
    const float* qnw    = (const float*)d_in[4];
    const float* knw    = (const float*)d_in[5];
    const float* proj_w = (const float*)d_in[6];
    const float* proj_b = (const float*)d_in[7];
    float* out = (float*)d_out;

    char* ws = (char*)d_ws;
    ushort_t* xb    = (ushort_t*)(ws);                         // 8 MB
    ushort_t* wqkv  = (ushort_t*)(ws + 8388608);               // 6 MB
    ushort_t* wproj = (ushort_t*)(ws + 8388608 + 6291456);     // 2 MB
    ushort_t* qkvb  = (ushort_t*)(ws + 16777216);              // 24 MB
    ushort_t* qhp   = (ushort_t*)(ws + 16777216 + 25165824);   // 8 MB
    ushort_t* khp   = (ushort_t*)(ws + 16777216 + 25165824 + 8388608);
    ushort_t* vtp   = (ushort_t*)(ws + 16777216 + 25165824 + 2 * 8388608);
    ushort_t* obp   = qkvb;  // reuse qkv region

    f32_to_bf16_k<<<MTOT * DIM / 1024, 256, 0, stream>>>(x, xb, MTOT * DIM);
    f32_to_bf16_k<<<3 * DIM * DIM / 1024, 256, 0, stream>>>(qkv_w, wqkv, 3 * DIM * DIM);
    f32_to_bf16_k<<<DIM * DIM / 1024, 256, 0, stream>>>(proj_w, wproj, DIM * DIM);

    gemm_bt<1><<<dim3(3 * DIM / 128, MTOT / 128), 256, 0, stream>>>(xb, wqkv, qkv_b, qkvb,
                                                                    MTOT, 3 * DIM, DIM);
    norm_rope_k<<<dim3(32, 3, 32), 256, 0, stream>>>(qkvb, pe, qnw, knw, qhp, khp, vtp);
    attn_k<<<dim3(16, 32), 256, 0, stream>>>(qhp, khp, vtp, obp);
    gemm_bt<0><<<dim3(DIM / 128, MTOT / 128), 256, 0, stream>>>(obp, wproj, proj_b, out,
                                                                MTOT, DIM, DIM);
}